// Round 6
// baseline (38.482 us; speedup 1.0000x reference)
//
#include <hip/hip_runtime.h>

#define NC 5
#define NB 2
#define SPATIAL (128*128*128)
#define NVEC (SPATIAL/4)
#define SMOOTHF 1e-5f

// ws layout: slots[b][gx][16] floats — per-block partials, fully overwritten
// every launch (no zeroing, no atomics, no init kernel).

// Register discipline (hard-won):
//  R2: __launch_bounds__(256,8) -> forced VGPR 32 -> 160 MB scratch spill. Never.
//  R3: #pragma unroll on 2 iters -> 68 VGPR -> over the 64-VGPR cliff.
//  R4: device-scope threadfence + done-counter per block -> 6x serialization. Never.
//  R5: rolled loop, 44 VGPR, but 3 serial dispatches -> this round merges them.
__global__ __launch_bounds__(256) void dpdc_main(
    const float* __restrict__ net, const void* __restrict__ targ,
    const float* __restrict__ dist, float* __restrict__ slots)
{
    const int b = blockIdx.y;

    // in-kernel int64-vs-int32 detection: first 64 u64 words of target.
    // int64 data: all values in [0,5) -> ballot 0. int32 data: some odd-indexed
    // value is nonzero -> as u64 >= 2^32 -> ballot != 0.
    const unsigned long long tv =
        ((const unsigned long long*)targ)[threadIdx.x & 63];
    const int t64 = (__ballot(tv >= 5ull) == 0ull);

    const float4* nb = (const float4*)(net + (size_t)b * NC * SPATIAL);
    const float4* db = (const float4*)(dist + (size_t)b * SPATIAL);
    const int4* t32p = (const int4*)((const int*)targ + (size_t)b * SPATIAL);
    const ulonglong2* t64p =
        (const ulonglong2*)((const unsigned long long*)targ + (size_t)b * SPATIAL);

    float tp[NC], sp[NC], cnt[NC];
    #pragma unroll
    for (int c = 0; c < NC; ++c) { tp[c] = 0.f; sp[c] = 0.f; cnt[c] = 0.f; }
    float nll = 0.f;

    int i = blockIdx.x * 256 + threadIdx.x;
    const int stride = gridDim.x * 256;
    #pragma unroll 1
    for (; i < NVEC; i += stride) {
        float4 l[NC];
        #pragma unroll
        for (int c = 0; c < NC; ++c) l[c] = nb[(size_t)c * NVEC + i];
        float4 dd = db[i];
        int tt[4];
        if (t64) {
            ulonglong2 a = t64p[2 * i];
            ulonglong2 bq = t64p[2 * i + 1];
            tt[0] = (int)a.x; tt[1] = (int)a.y;
            tt[2] = (int)bq.x; tt[3] = (int)bq.y;
        } else {
            int4 a = t32p[i];
            tt[0] = a.x; tt[1] = a.y; tt[2] = a.z; tt[3] = a.w;
        }
        const float* dv = (const float*)&dd;
        #pragma unroll
        for (int j = 0; j < 4; ++j) {
            float lc[NC];
            #pragma unroll
            for (int c = 0; c < NC; ++c) lc[c] = ((const float*)&l[c])[j];
            float m = fmaxf(fmaxf(fmaxf(lc[0], lc[1]), fmaxf(lc[2], lc[3])), lc[4]);
            float e[NC];
            float s = 0.f;
            #pragma unroll
            for (int c = 0; c < NC; ++c) { e[c] = __expf(lc[c] - m); s += e[c]; }
            float inv = 1.0f / s;
            int t = tt[j];
            float lsel = lc[4];
            #pragma unroll
            for (int c = 0; c < 4; ++c) lsel = (t == c) ? lc[c] : lsel;
            float pd = dv[j] * inv;  // dist / sumexp
            #pragma unroll
            for (int c = 0; c < NC; ++c) {
                float p = e[c] * inv;
                sp[c] += p;
                tp[c] += (t == c) ? e[c] * pd : 0.f;
                cnt[c] += (t == c) ? 1.f : 0.f;
            }
            nll += __logf(s) - (lsel - m);
        }
    }

    // block reduction of 16 scalars: tp[5], sp[5], cnt[5], nll
    __shared__ float red[4][16];
    float vals[16];
    #pragma unroll
    for (int c = 0; c < NC; ++c) {
        vals[c] = tp[c]; vals[5 + c] = sp[c]; vals[10 + c] = cnt[c];
    }
    vals[15] = nll;
    const int lane = threadIdx.x & 63;
    const int wave = threadIdx.x >> 6;
    #pragma unroll
    for (int k = 0; k < 16; ++k) {
        float v = vals[k];
        #pragma unroll
        for (int off = 32; off > 0; off >>= 1) v += __shfl_down(v, off, 64);
        if (lane == 0) red[wave][k] = v;
    }
    __syncthreads();
    if (threadIdx.x < 16) {
        int k = threadIdx.x;
        float v = red[0][k] + red[1][k] + red[2][k] + red[3][k];
        slots[((size_t)b * gridDim.x + blockIdx.x) * 16 + k] = v;  // plain store
    }
}

__global__ __launch_bounds__(1024) void finalize(const float* __restrict__ slots,
                                                 int gx, float* __restrict__ out) {
    // 32 logical sums: (b,k) with b in [0,2), k in [0,16). Thread j handles
    // pair p=j&31, slot-chunk j>>5 (32 chunks).
    __shared__ float part[1024];
    __shared__ float tot[32];
    const int j = threadIdx.x;
    const int p = j & 31;
    const int b = p >> 4, k = p & 15;
    float s = 0.f;
    for (int slot = j >> 5; slot < gx; slot += 32)
        s += slots[((size_t)b * gx + slot) * 16 + k];
    part[j] = s;
    __syncthreads();
    if (j < 32) {
        float t = 0.f;
        #pragma unroll
        for (int m = 0; m < 32; ++m) t += part[j + 32 * m];
        tot[j] = t;
    }
    __syncthreads();
    if (j == 0) {
        float dcsum = 0.f;
        for (int bb = 0; bb < NB; ++bb)
            for (int c = 0; c < NC; ++c) {
                float tpv = tot[bb * 16 + c];
                float spv = tot[bb * 16 + 5 + c];
                float cv  = tot[bb * 16 + 10 + c];
                dcsum += (2.f * tpv + SMOOTHF) / (spv + cv + SMOOTHF);
            }
        float ce = (tot[15] + tot[31]) / (float)((size_t)NB * SPATIAL);
        out[0] = ce - dcsum / (float)(NB * NC);
    }
}

extern "C" void kernel_launch(void* const* d_in, const int* in_sizes, int n_in,
                              void* d_out, int out_size, void* d_ws, size_t ws_size,
                              hipStream_t stream) {
    const float* net  = (const float*)d_in[0];
    const void*  targ = d_in[1];
    const float* dist = (const float*)d_in[2];
    float* slots = (float*)d_ws;

    int gx = 1024;  // 2 float4-groups per thread at gx=1024
    while ((size_t)NB * gx * 16 * sizeof(float) > ws_size && gx > 1) gx >>= 1;

    dim3 grid(gx, NB);
    dpdc_main<<<grid, 256, 0, stream>>>(net, targ, dist, slots);
    finalize<<<1, 1024, 0, stream>>>(slots, gx, (float*)d_out);
}

// Round 7
// 33.505 us; speedup vs baseline: 1.1485x; 1.1485x over previous
//
#include <hip/hip_runtime.h>

#define NC 5
#define NB 2
#define SPATIAL (128*128*128)
#define NGROUPS (SPATIAL/4)              // float4 groups per batch = 524288
#define TILE_GROUPS 256                  // groups per tile (1 per thread)
#define NTILES (NGROUPS/TILE_GROUPS)     // 2048 tiles per batch
#define GX 256                           // blocks per batch
#define TPB (NTILES/GX)                  // 8 tiles per block
#define SMOOTHF 1e-5f

// LDS tile layout (bytes): [0,20480) net (c*4096); [20480,24576) dist;
//                          [24576,32768) targ (8KB int64 / 4KB int32)
#define TILE_BYTES (32*1024)

// Register/structure discipline (hard-won):
//  R2: __launch_bounds__(256,8) -> forced 32 VGPR -> 160MB scratch spill. Never.
//  R3: unrolled 2 iters -> 68 VGPR -> over 64-VGPR cliff; perf == R5 anyway.
//  R4: device-fence + done-counter per block -> 6x serialization. Never.
//  R5/R6: ~35us wall invariant to grid/VGPR/dispatch count -> latency-bound
//         (waves x MLP saturated). This round: async global_load_lds double
//         buffer so next tile's loads fly under current tile's compute.

__device__ __forceinline__ void async16(const void* g, void* l) {
    __builtin_amdgcn_global_load_lds(
        (const __attribute__((address_space(1))) void*)g,
        (__attribute__((address_space(3))) void*)l, 16, 0, 0);
}

__global__ __launch_bounds__(256) void dpdc_main(
    const float* __restrict__ net, const void* __restrict__ targ,
    const float* __restrict__ dist, float* __restrict__ slots)
{
    __shared__ __align__(16) char lds[2][TILE_BYTES];
    const int b   = blockIdx.y;
    const int tid = threadIdx.x;

    // int64-vs-int32 detection (uniform): first 64 u64 words of target.
    const unsigned long long tv = ((const unsigned long long*)targ)[tid & 63];
    const int t64 = (__ballot(tv >= 5ull) == 0ull);

    const char* netb  = (const char*)net  + (size_t)b * NC * SPATIAL * 4;
    const char* distb = (const char*)dist + (size_t)b * SPATIAL * 4;
    const char* targb = (const char*)targ + (size_t)b * SPATIAL * (t64 ? 8 : 4);

    const int tl0 = blockIdx.x * TPB;    // first tile of this block

    // ---- stage one tile (async, 7-8 x 16B per thread) ----
    auto stage = [&](int tl, int bf) {
        char* base = &lds[bf][0];
        const size_t toff = (size_t)tl * 4096 + tid * 16;   // 4KB per region per tile
        #pragma unroll
        for (int c = 0; c < NC; ++c)
            async16(netb + (size_t)c * SPATIAL * 4 + toff, base + c * 4096 + tid * 16);
        async16(distb + toff, base + 20480 + tid * 16);
        if (t64) {
            const char* ts = targb + (size_t)tl * 8192 + tid * 16;
            async16(ts,        base + 24576 + tid * 16);
            async16(ts + 4096, base + 28672 + tid * 16);
        } else {
            async16(targb + toff, base + 24576 + tid * 16);
        }
    };

    float tp[NC], sp[NC], cnt[NC];
    #pragma unroll
    for (int c = 0; c < NC; ++c) { tp[c] = 0.f; sp[c] = 0.f; cnt[c] = 0.f; }
    float nll = 0.f;

    stage(tl0, 0);
    __syncthreads();                 // built-in vmcnt(0) drain + barrier

    #pragma unroll 1
    for (int k = 0; k < TPB; ++k) {
        if (k + 1 < TPB) stage(tl0 + k + 1, (k + 1) & 1);   // fly under compute

        const char* base = &lds[k & 1][0];
        float4 l[NC];
        #pragma unroll
        for (int c = 0; c < NC; ++c)
            l[c] = *(const float4*)(base + c * 4096 + tid * 16);
        float4 dd = *(const float4*)(base + 20480 + tid * 16);
        int tt[4];
        if (t64) {
            ulonglong2 a = *(const ulonglong2*)(base + 24576 + tid * 32);
            ulonglong2 q = *(const ulonglong2*)(base + 24576 + tid * 32 + 16);
            tt[0] = (int)a.x; tt[1] = (int)a.y;
            tt[2] = (int)q.x; tt[3] = (int)q.y;
        } else {
            int4 a = *(const int4*)(base + 24576 + tid * 16);
            tt[0] = a.x; tt[1] = a.y; tt[2] = a.z; tt[3] = a.w;
        }
        const float* dv = (const float*)&dd;
        #pragma unroll
        for (int j = 0; j < 4; ++j) {
            float lc[NC];
            #pragma unroll
            for (int c = 0; c < NC; ++c) lc[c] = ((const float*)&l[c])[j];
            float m = fmaxf(fmaxf(fmaxf(lc[0], lc[1]), fmaxf(lc[2], lc[3])), lc[4]);
            float e[NC];
            float s = 0.f;
            #pragma unroll
            for (int c = 0; c < NC; ++c) { e[c] = __expf(lc[c] - m); s += e[c]; }
            float inv = 1.0f / s;
            int t = tt[j];
            float lsel = lc[4];
            #pragma unroll
            for (int c = 0; c < 4; ++c) lsel = (t == c) ? lc[c] : lsel;
            float pd = dv[j] * inv;
            #pragma unroll
            for (int c = 0; c < NC; ++c) {
                float p = e[c] * inv;
                sp[c] += p;
                tp[c] += (t == c) ? e[c] * pd : 0.f;
                cnt[c] += (t == c) ? 1.f : 0.f;
            }
            nll += __logf(s) - (lsel - m);
        }
        __syncthreads();             // drains next tile's async loads + fences bufs
    }

    // block reduction of 16 scalars: tp[5], sp[5], cnt[5], nll
    __shared__ float red[4][16];
    float vals[16];
    #pragma unroll
    for (int c = 0; c < NC; ++c) {
        vals[c] = tp[c]; vals[5 + c] = sp[c]; vals[10 + c] = cnt[c];
    }
    vals[15] = nll;
    const int lane = tid & 63;
    const int wave = tid >> 6;
    #pragma unroll
    for (int k = 0; k < 16; ++k) {
        float v = vals[k];
        #pragma unroll
        for (int off = 32; off > 0; off >>= 1) v += __shfl_down(v, off, 64);
        if (lane == 0) red[wave][k] = v;
    }
    __syncthreads();
    if (tid < 16) {
        float v = red[0][tid] + red[1][tid] + red[2][tid] + red[3][tid];
        slots[((size_t)b * GX + blockIdx.x) * 16 + tid] = v;   // plain store
    }
}

__global__ __launch_bounds__(1024) void finalize(const float* __restrict__ slots,
                                                 float* __restrict__ out) {
    __shared__ float part[1024];
    __shared__ float tot[32];
    const int j = threadIdx.x;
    const int p = j & 31;
    const int b = p >> 4, k = p & 15;
    float s = 0.f;
    for (int slot = j >> 5; slot < GX; slot += 32)
        s += slots[((size_t)b * GX + slot) * 16 + k];
    part[j] = s;
    __syncthreads();
    if (j < 32) {
        float t = 0.f;
        #pragma unroll
        for (int m = 0; m < 32; ++m) t += part[j + 32 * m];
        tot[j] = t;
    }
    __syncthreads();
    if (j == 0) {
        float dcsum = 0.f;
        for (int bb = 0; bb < NB; ++bb)
            for (int c = 0; c < NC; ++c) {
                float tpv = tot[bb * 16 + c];
                float spv = tot[bb * 16 + 5 + c];
                float cv  = tot[bb * 16 + 10 + c];
                dcsum += (2.f * tpv + SMOOTHF) / (spv + cv + SMOOTHF);
            }
        float ce = (tot[15] + tot[31]) / (float)((size_t)NB * SPATIAL);
        out[0] = ce - dcsum / (float)(NB * NC);
    }
}

extern "C" void kernel_launch(void* const* d_in, const int* in_sizes, int n_in,
                              void* d_out, int out_size, void* d_ws, size_t ws_size,
                              hipStream_t stream) {
    const float* net  = (const float*)d_in[0];
    const void*  targ = d_in[1];
    const float* dist = (const float*)d_in[2];
    float* slots = (float*)d_ws;     // NB*GX*16 floats = 32 KB, fully overwritten

    dim3 grid(GX, NB);
    dpdc_main<<<grid, 256, 0, stream>>>(net, targ, dist, slots);
    finalize<<<1, 1024, 0, stream>>>(slots, (float*)d_out);
}